// Round 1
// 359.001 us; speedup vs baseline: 1.0617x; 1.0617x over previous
//
#include <hip/hip_runtime.h>
#include <stdint.h>

// m_btabl — round 4: async-streamed stage-1.
//
// Diagnosis from r3 counters: latency-bound (VALU 13.6%, Mfma 2.6%, HBM 8%,
// ~1 block/CU effective). Stage-1's register-held, lane-divergent x loads
// (68 VGPRs!) exposed serial HBM round-trips with ~2 KB/CU in flight.
//
// This version:
//  * stage-1 x is streamed via __builtin_amdgcn_global_load_lds (16B units,
//    linear LDS dest) into a double-buffered 8-sample chunk (12.8 KB),
//    8 rounds/block, counted s_waitcnt vmcnt(3) + RAW s_barrier (no
//    __syncthreads inside the pipeline: it would drain vmcnt(0)).
//  * stage-1 compute: one (sample,row) job per thread (320 jobs/round) from
//    LDS; W2 hoisted to registers once.
//  * one-hot K-augmentation written once up front (x-independent).
//  * __launch_bounds__(NTM, 1) so the compiler stops starving VGPRs.
//  * stage-2 MFMA + epilogue + stage-3 tail unchanged from r3.
//
// LDS = 74,976 B -> 2 blocks/CU; block A's MFMA/tail overlaps block B's stream.
//
// ws layout (floats) from prep_kernel (unchanged):
//   [0,3096)     W1 image, bf16 ushort[129*48] (bias folded at k=40..44, row128=0)
//   [3096,3608)  w1b pack f32 [128][4]
//   [3608,3644)  consts: Wm(25, diag 0.2) | W2b(5) | TB(3) | lam | pad
//   [3644,3694)  W2s (50)

typedef short bf16x8 __attribute__((ext_vector_type(8)));
typedef float f32x4v __attribute__((ext_vector_type(4)));

#define NTP 256
#define NTM 320
#define GAS __attribute__((address_space(1)))
#define LAS __attribute__((address_space(3)))

__device__ __forceinline__ unsigned short f2bf(float f) {
    unsigned int u = __float_as_uint(f);
    u += 0x7FFFu + ((u >> 16) & 1u);   // round-to-nearest-even
    return (unsigned short)(u >> 16);
}

// ---------------- prep kernel (unchanged) ----------------
__device__ __forceinline__ float block_reduce_sum(float v, float* red, int tid) {
    #pragma unroll
    for (int off = 32; off > 0; off >>= 1) v += __shfl_xor(v, off, 64);
    if ((tid & 63) == 0) red[tid >> 6] = v;
    __syncthreads();
    float r = red[0] + red[1] + red[2] + red[3];
    __syncthreads();
    return r;
}

__global__ __launch_bounds__(NTP)
void prep_kernel(const float* __restrict__ W1, const float* __restrict__ W2,
                 const float* __restrict__ B,  const float* __restrict__ Tw1,
                 const float* __restrict__ Tw, const float* __restrict__ Tw2,
                 const float* __restrict__ TB, const float* __restrict__ l,
                 float* __restrict__ ws)
{
    __shared__ float red[4];
    const int tid = threadIdx.x;
    float ss;
    ss = 0.f; for (int i = tid; i < 4800; i += NTP) { float w = W1[i];  ss += w*w; }
    const float n1 = sqrtf(block_reduce_sum(ss, red, tid));
    ss = 0.f; for (int i = tid; i < 50;   i += NTP) { float w = W2[i];  ss += w*w; }
    const float n2 = sqrtf(block_reduce_sum(ss, red, tid));
    ss = 0.f; for (int i = tid; i < 360;  i += NTP) { float w = Tw1[i]; ss += w*w; }
    const float n3 = sqrtf(block_reduce_sum(ss, red, tid));
    ss = 0.f; for (int i = tid; i < 25;   i += NTP) { float w = Tw[i];  ss += w*w; }
    const float n4 = sqrtf(block_reduce_sum(ss, red, tid));
    ss = 0.f; for (int i = tid; i < 5;    i += NTP) { float w = Tw2[i]; ss += w*w; }
    const float n5 = sqrtf(block_reduce_sum(ss, red, tid));

    const float s1 = n1 > 10.f ? 10.f/(1e-8f+n1) : 1.f;
    const float s2 = n2 > 10.f ? 10.f/(1e-8f+n2) : 1.f;
    const float s3 = n3 > 10.f ? 10.f/(1e-8f+n3) : 1.f;
    const float s4 = n4 > 10.f ? 10.f/(1e-8f+n4) : 1.f;
    const float s5 = n5 > 10.f ? 10.f/(1e-8f+n5) : 1.f;

    unsigned short* img = (unsigned short*)ws;
    for (int i = tid; i < 129*48; i += NTP) {
        const int e = i / 48, k = i - e*48;
        float v = 0.f;
        if (e < 120) {
            if (k < 40)      v = W1[e*40 + k] * s1;
            else if (k < 45) v = B[e*5 + (k-40)];
        }
        img[i] = f2bf(v);
    }
    for (int i = tid; i < 512; i += NTP) {
        const int e = i >> 2, c = i & 3;
        ws[3096 + i] = (c < 3 && e < 120) ? Tw1[c*120 + e] * s3 : 0.f;
    }
    for (int i = tid; i < 36; i += NTP) {
        float v = 0.f;
        if (i < 25)      { int r = i/5, c = i - r*5; v = (r == c) ? 0.2f : Tw[i]*s4; }
        else if (i < 30) v = Tw2[i-25] * s5;
        else if (i < 33) v = TB[i-30];
        else if (i == 33){ float lv = l[0]; v = fminf(fmaxf(lv, 0.f), 1.f); }
        ws[3608 + i] = v;
    }
    for (int i = tid; i < 50; i += NTP) ws[3644 + i] = W2[i] * s2;
}

// ---------------- main kernel ----------------

// one 8-sample chunk = 12,800 B = 800 x 16B units; wave w moves units
// [w*160, w*160+160) (2 full wave instrs + 1 half). LDS dest is linear
// (wave-uniform base + lane*16 — HW semantics), global src is per-lane.
__device__ __forceinline__ void stage_chunk(const char* xB, size_t base, size_t gmax,
                                            float* lbuf, int wave, int lane)
{
    #pragma unroll
    for (int i = 0; i < 3; i++) {
        if (i < 2 || lane < 32) {
            const int unit = wave*160 + i*64 + lane;
            size_t go = base + (size_t)unit*16;
            if (go > gmax) go = gmax;                       // tail-safe (16B aligned)
            __builtin_amdgcn_global_load_lds(
                (const GAS unsigned int*)(xB + go),
                (LAS unsigned int*)(lbuf + (wave*160 + i*64)*4),
                16, 0, 0);
        }
    }
}

__global__ __launch_bounds__(NTM, 1)
void btabl_main(const float* __restrict__ x, const float* __restrict__ ws,
                float* __restrict__ out, int nsamp)
{
    __align__(16) __shared__ unsigned short sW1[129*48];       // 12384 B
    __align__(16) __shared__ float          sWp[128*4];        // 2048 B
    __align__(16) __shared__ float          sC[36];            // 144 B
    __align__(16) __shared__ float          sW2[52];           // 208 B
    __align__(16) __shared__ unsigned short sZ[320*48 + 16];   // 30752 B (+overflow pad)
    __align__(16) __shared__ float          sX3[320*3];        // 3840 B
    __align__(16) __shared__ float          xb[2][3200];       // 2 x 12800 B x-chunks

    const int tid  = threadIdx.x;
    const int wave = tid >> 6;
    const int lane = tid & 63;

    // ---- stage weights into LDS ----
    {
        const float4* src = (const float4*)ws;
        float4* d1 = (float4*)sW1;
        #pragma unroll
        for (int i = 0; i < 3; i++) {
            const int idx = tid + i*NTM;
            if (idx < 774) d1[idx] = src[idx];
        }
        if (tid < 128) ((float4*)sWp)[tid] = src[774 + tid];
        if (tid < 9)   ((float4*)sC)[tid]  = src[902 + tid];
        if (tid < 12)  ((float4*)sW2)[tid] = src[911 + tid];   // floats 3644..3691
        if (tid < 2)   sW2[48 + tid] = ws[3692 + tid];         // floats 3692..3693
    }

    // ---- one-hot K-augmentation (k=40..47) for col = tid — x-independent ----
    {
        bf16x8 oh = {0,0,0,0,0,0,0,0};
        oh[tid % 5] = (short)0x3F80;                           // bf16 1.0 at k=40+col%5
        *(bf16x8*)(sZ + tid*48 + 40) = oh;
    }

    __syncthreads();   // weights + sW2 visible (also drains all vmem: clean slate)

    // ---- stage 1: async-pipelined x stream + Z compute ----
    const int sC8 = tid / 40;                 // sample within 8-sample chunk
    const int dR  = tid - sC8*40;             // row (d index)
    const char*  xB        = (const char*)x;
    const size_t blockBase = (size_t)blockIdx.x * 102400;      // 64*400*4 bytes
    const size_t gmax      = (size_t)nsamp * 1600 - 16;

    stage_chunk(xB, blockBase,          gmax, xb[0], wave, lane);   // c0
    stage_chunk(xB, blockBase + 12800,  gmax, xb[1], wave, lane);   // c1

    // W2 -> registers (one-time LDS broadcast read)
    float W2r[50];
    #pragma unroll
    for (int i = 0; i < 50; i++) W2r[i] = sW2[i];

    #pragma unroll
    for (int r = 0; r < 8; r++) {
        float* xbuf = xb[r & 1];
        // counted wait: my chunk-r loads done; chunk r+1's 3 instrs may remain
        // in flight across the barrier (never drain to 0 mid-loop).
        if (r < 7) { asm volatile("s_waitcnt vmcnt(3)" ::: "memory"); }
        else       { asm volatile("s_waitcnt vmcnt(0)" ::: "memory"); }
        asm volatile("s_barrier" ::: "memory");   // raw: no implicit vmcnt(0) drain

        // job: row dR of sample sC8 -> Z row (5 outputs)
        const float* xr = xbuf + sC8*400 + dR*10;
        float xf[10];
        #pragma unroll
        for (int q = 0; q < 5; q++) {
            const float2 v = *(const float2*)(xr + q*2);      // 8B-aligned ds_read
            xf[2*q] = v.x; xf[2*q+1] = v.y;
        }
        float z[5];
        #pragma unroll
        for (int t = 0; t < 5; t++) {
            float a = 0.f;
            #pragma unroll
            for (int k = 0; k < 10; k++) a = fmaf(xf[k], W2r[k*5+t], a);
            z[t] = a;
        }
        const int colB = (r*8 + sC8)*5;
        unsigned short* zp = sZ + colB*48 + dR;
        #pragma unroll
        for (int t = 0; t < 5; t++) zp[t*48] = f2bf(z[t]);

        asm volatile("s_barrier" ::: "memory");   // all reads of xbuf done
        if (r < 6)
            stage_chunk(xB, blockBase + (size_t)(r+2)*12800, gmax, xb[r & 1], wave, lane);
    }
    __syncthreads();   // full drain before MFMA phase reads sZ/sW1/sWp

    // ---- stage 2: MFMA GEMM + X3 epilogue (unchanged from r3) ----
    const int quad = lane >> 4;
    const int m    = lane & 15;
    const int colBase = wave * 64;

    bf16x8 Bf[4][2];
    const bf16x8 z8 = {0,0,0,0,0,0,0,0};
    #pragma unroll
    for (int nt = 0; nt < 4; nt++) {
        const int col = colBase + nt*16 + m;
        Bf[nt][0] = *(const bf16x8*)(sZ + col*48 + quad*8);
        bf16x8 b1 = *(const bf16x8*)(sZ + col*48 + 32 + quad*8);  // quads 2,3 overflow
        Bf[nt][1] = (quad >= 2) ? z8 : b1;                         // k>=48 pad -> 0
    }

    float X3p[4][3];
    #pragma unroll
    for (int nt = 0; nt < 4; nt++)
        #pragma unroll
        for (int j = 0; j < 3; j++) X3p[nt][j] = 0.f;

    const f32x4v zacc = {0.f, 0.f, 0.f, 0.f};
    #pragma unroll
    for (int mt = 0; mt < 8; mt++) {
        const unsigned short* arow = sW1 + (mt*16 + m)*48;
        const bf16x8 A0 = *(const bf16x8*)(arow + quad*8);
        const bf16x8 A1 = *(const bf16x8*)(arow + 32 + quad*8);   // overflow -> row128=0
        f32x4v wp[4];
        #pragma unroll
        for (int r = 0; r < 4; r++)
            wp[r] = *(const f32x4v*)(sWp + (mt*16 + quad*4 + r)*4);
        #pragma unroll
        for (int nt = 0; nt < 4; nt++) {
            f32x4v acc = __builtin_amdgcn_mfma_f32_16x16x32_bf16(A0, Bf[nt][0], zacc, 0, 0, 0);
            acc = __builtin_amdgcn_mfma_f32_16x16x32_bf16(A1, Bf[nt][1], acc, 0, 0, 0);
            #pragma unroll
            for (int r = 0; r < 4; r++) {
                const float h = fmaxf(acc[r], 0.f);               // bias folded in GEMM
                X3p[nt][0] = fmaf(wp[r][0], h, X3p[nt][0]);
                X3p[nt][1] = fmaf(wp[r][1], h, X3p[nt][1]);
                X3p[nt][2] = fmaf(wp[r][2], h, X3p[nt][2]);
            }
        }
    }

    #pragma unroll
    for (int nt = 0; nt < 4; nt++) {
        #pragma unroll
        for (int j = 0; j < 3; j++) {
            float v = X3p[nt][j];
            v += __shfl_xor(v, 16, 64);
            v += __shfl_xor(v, 32, 64);
            X3p[nt][j] = v;
        }
    }
    if (quad == 0) {
        #pragma unroll
        for (int nt = 0; nt < 4; nt++) {
            const int col = colBase + nt*16 + m;
            sX3[col*3 + 0] = X3p[nt][0];
            sX3[col*3 + 1] = X3p[nt][1];
            sX3[col*3 + 2] = X3p[nt][2];
        }
    }
    __syncthreads();

    // ---- stage 3: attention + output softmax, one thread per sample ----
    if (tid < 64) {
        const int sGlob = blockIdx.x * 64 + tid;
        float X3v[3][5];
        #pragma unroll
        for (int t = 0; t < 5; t++)
            #pragma unroll
            for (int j = 0; j < 3; j++)
                X3v[j][t] = sX3[(tid*5 + t)*3 + j];

        const float lam  = sC[33];
        const float olam = 1.f - lam;
        float y[3];
        #pragma unroll
        for (int j = 0; j < 3; j++) {
            float S[5];
            #pragma unroll
            for (int t = 0; t < 5; t++) {
                float a = 0.f;
                #pragma unroll
                for (int k = 0; k < 5; k++)
                    a = fmaf(X3v[j][k], sC[k*5 + t], a);
                S[t] = a;
            }
            float mx = S[0];
            #pragma unroll
            for (int t = 1; t < 5; t++) mx = fmaxf(mx, S[t]);
            float ex[5], se = 0.f;
            #pragma unroll
            for (int t = 0; t < 5; t++) { ex[t] = __expf(S[t] - mx); se += ex[t]; }
            const float inv = 1.f / se;
            float yj = sC[30 + j];
            #pragma unroll
            for (int t = 0; t < 5; t++) {
                const float a  = ex[t] * inv;
                const float xc = X3v[j][t] * (lam + olam * a);
                yj = fmaf(xc, sC[25 + t], yj);
            }
            y[j] = yj;
        }
        const float mx = fmaxf(y[0], fmaxf(y[1], y[2]));
        const float e0 = __expf(y[0]-mx), e1 = __expf(y[1]-mx), e2 = __expf(y[2]-mx);
        const float inv = 1.f / (e0 + e1 + e2);
        if (sGlob < nsamp) {
            float* o = out + (size_t)sGlob*3;
            o[0] = e0*inv; o[1] = e1*inv; o[2] = e2*inv;
        }
    }
}

extern "C" void kernel_launch(void* const* d_in, const int* in_sizes, int n_in,
                              void* d_out, int out_size, void* d_ws, size_t ws_size,
                              hipStream_t stream) {
    const float* x   = (const float*)d_in[0];
    const float* W1  = (const float*)d_in[1];
    const float* W2  = (const float*)d_in[2];
    const float* B   = (const float*)d_in[3];
    const float* Tw1 = (const float*)d_in[4];
    const float* Tw  = (const float*)d_in[5];
    const float* Tw2 = (const float*)d_in[6];
    const float* TB  = (const float*)d_in[7];
    const float* l   = (const float*)d_in[8];
    float* out = (float*)d_out;
    float* ws  = (float*)d_ws;

    hipLaunchKernelGGL(prep_kernel, dim3(1), dim3(NTP), 0, stream,
                       W1, W2, B, Tw1, Tw, Tw2, TB, l, ws);

    const int nsamp = in_sizes[0] / 400;
    const int grid  = (nsamp + 63) / 64;
    hipLaunchKernelGGL(btabl_main, dim3(grid), dim3(NTM), 0, stream,
                       x, ws, out, nsamp);
}

// Round 2
// 334.165 us; speedup vs baseline: 1.1406x; 1.0743x over previous
//
#include <hip/hip_runtime.h>
#include <stdint.h>

// m_btabl — round 5: register-streamed stage-1, zero barriers, 3 blocks/CU.
//
// r4 post-mortem: global_load_lds + C-level ds_read of the SAME LDS buffer
// makes the waitcnt legalizer insert s_waitcnt vmcnt(0) before the reads
// (can't disprove LDS-DMA aliasing) -> every round drained the prefetch;
// plus 16 barriers/block convoyed all 5 waves with only 2 blocks/CU.
//
// r5: stage-1 is remapped so each thread CONSUMES WHAT IT LOADS:
//   thread p -> row-pair r20=p%20 (80 B, 16B-aligned) of sample s16=p/20;
//   4 rounds x 16 samples: 5x float4 global->reg, 100 FMA (W2 via uniform
//   s_load from ws -> SGPRs), bf16-pair pack, 5x ds_write_b32 into sZ.
//   No LDS staging of x, no barriers inside stage-1 -> compiler emits
//   counted vmcnt on register deps and hoists loads; 15 waves/CU of TLP
//   saturate HBM without any hand pipeline.
// LDS = 49,168 B -> 3 blocks/CU. __launch_bounds__(320,4) caps VGPR<=128
// so 15 waves/CU actually fit.
// Stage-2 MFMA + epilogue + stage-3 tail unchanged (proven r3/r4).
//
// ws layout (floats) from prep_kernel (unchanged):
//   [0,3096)     W1 image, bf16 ushort[129*48] (bias folded at k=40..44, row128=0)
//   [3096,3608)  w1b pack f32 [128][4]
//   [3608,3644)  consts: Wm(25, diag 0.2) | W2b(5) | TB(3) | lam | pad
//   [3644,3694)  W2s (50)

typedef short bf16x8 __attribute__((ext_vector_type(8)));
typedef float f32x4v __attribute__((ext_vector_type(4)));

#define NTP 256
#define NTM 320

__device__ __forceinline__ unsigned short f2bf(float f) {
    unsigned int u = __float_as_uint(f);
    u += 0x7FFFu + ((u >> 16) & 1u);   // round-to-nearest-even
    return (unsigned short)(u >> 16);
}

// ---------------- prep kernel (unchanged) ----------------
__device__ __forceinline__ float block_reduce_sum(float v, float* red, int tid) {
    #pragma unroll
    for (int off = 32; off > 0; off >>= 1) v += __shfl_xor(v, off, 64);
    if ((tid & 63) == 0) red[tid >> 6] = v;
    __syncthreads();
    float r = red[0] + red[1] + red[2] + red[3];
    __syncthreads();
    return r;
}

__global__ __launch_bounds__(NTP)
void prep_kernel(const float* __restrict__ W1, const float* __restrict__ W2,
                 const float* __restrict__ B,  const float* __restrict__ Tw1,
                 const float* __restrict__ Tw, const float* __restrict__ Tw2,
                 const float* __restrict__ TB, const float* __restrict__ l,
                 float* __restrict__ ws)
{
    __shared__ float red[4];
    const int tid = threadIdx.x;
    float ss;
    ss = 0.f; for (int i = tid; i < 4800; i += NTP) { float w = W1[i];  ss += w*w; }
    const float n1 = sqrtf(block_reduce_sum(ss, red, tid));
    ss = 0.f; for (int i = tid; i < 50;   i += NTP) { float w = W2[i];  ss += w*w; }
    const float n2 = sqrtf(block_reduce_sum(ss, red, tid));
    ss = 0.f; for (int i = tid; i < 360;  i += NTP) { float w = Tw1[i]; ss += w*w; }
    const float n3 = sqrtf(block_reduce_sum(ss, red, tid));
    ss = 0.f; for (int i = tid; i < 25;   i += NTP) { float w = Tw[i];  ss += w*w; }
    const float n4 = sqrtf(block_reduce_sum(ss, red, tid));
    ss = 0.f; for (int i = tid; i < 5;    i += NTP) { float w = Tw2[i]; ss += w*w; }
    const float n5 = sqrtf(block_reduce_sum(ss, red, tid));

    const float s1 = n1 > 10.f ? 10.f/(1e-8f+n1) : 1.f;
    const float s2 = n2 > 10.f ? 10.f/(1e-8f+n2) : 1.f;
    const float s3 = n3 > 10.f ? 10.f/(1e-8f+n3) : 1.f;
    const float s4 = n4 > 10.f ? 10.f/(1e-8f+n4) : 1.f;
    const float s5 = n5 > 10.f ? 10.f/(1e-8f+n5) : 1.f;

    unsigned short* img = (unsigned short*)ws;
    for (int i = tid; i < 129*48; i += NTP) {
        const int e = i / 48, k = i - e*48;
        float v = 0.f;
        if (e < 120) {
            if (k < 40)      v = W1[e*40 + k] * s1;
            else if (k < 45) v = B[e*5 + (k-40)];
        }
        img[i] = f2bf(v);
    }
    for (int i = tid; i < 512; i += NTP) {
        const int e = i >> 2, c = i & 3;
        ws[3096 + i] = (c < 3 && e < 120) ? Tw1[c*120 + e] * s3 : 0.f;
    }
    for (int i = tid; i < 36; i += NTP) {
        float v = 0.f;
        if (i < 25)      { int r = i/5, c = i - r*5; v = (r == c) ? 0.2f : Tw[i]*s4; }
        else if (i < 30) v = Tw2[i-25] * s5;
        else if (i < 33) v = TB[i-30];
        else if (i == 33){ float lv = l[0]; v = fminf(fmaxf(lv, 0.f), 1.f); }
        ws[3608 + i] = v;
    }
    for (int i = tid; i < 50; i += NTP) ws[3644 + i] = W2[i] * s2;
}

// ---------------- main kernel ----------------
__global__ __launch_bounds__(NTM, 4)
void btabl_main(const float* __restrict__ x, const float* __restrict__ ws,
                float* __restrict__ out, int nsamp)
{
    __align__(16) __shared__ unsigned short sW1[129*48];       // 12384 B
    __align__(16) __shared__ float          sWp[128*4];        // 2048 B
    __align__(16) __shared__ float          sC[36];            // 144 B
    __align__(16) __shared__ unsigned short sZ[320*48 + 16];   // 30752 B (+overflow pad)
    __align__(16) __shared__ float          sX3[320*3];        // 3840 B
    // total 49,168 B -> 3 blocks/CU

    const int tid  = threadIdx.x;
    const int wave = tid >> 6;
    const int lane = tid & 63;

    // ---- stage weights into LDS ----
    {
        const float4* src = (const float4*)ws;
        float4* d1 = (float4*)sW1;
        #pragma unroll
        for (int i = 0; i < 3; i++) {
            const int idx = tid + i*NTM;
            if (idx < 774) d1[idx] = src[idx];
        }
        if (tid < 128) ((float4*)sWp)[tid] = src[774 + tid];
        if (tid < 9)   ((float4*)sC)[tid]  = src[902 + tid];
    }

    // ---- one-hot K-augmentation (k=40..47) for col = tid — x-independent ----
    {
        bf16x8 oh = {0,0,0,0,0,0,0,0};
        oh[tid % 5] = (short)0x3F80;                           // bf16 1.0 at k=40+col%5
        *(bf16x8*)(sZ + tid*48 + 40) = oh;
    }
    __syncthreads();

    // ---- stage 1: register-streamed x -> Z (bf16) -> sZ. No barriers. ----
    // thread p: row-pair r20 = p%20 (rows 2*r20, 2*r20+1; 80 B, 16B-aligned)
    // of sample s16 = p/20 within the round; 4 rounds x 16 samples = 64.
    {
        const int p   = tid;
        const int s16 = p / 20;
        const int r20 = p - s16*20;
        const float* W2p = ws + 3644;                          // uniform -> s_load

        #pragma unroll
        for (int r = 0; r < 4; r++) {
            int sG = blockIdx.x*64 + r*16 + s16;
            sG = sG < nsamp ? sG : (nsamp - 1);                // tail-safe
            const float4* xv = (const float4*)(x + (size_t)sG*400 + r20*20);
            float xf[20];
            #pragma unroll
            for (int i = 0; i < 5; i++) {
                const float4 q = xv[i];                        // 5x global_load_dwordx4
                xf[i*4+0] = q.x; xf[i*4+1] = q.y; xf[i*4+2] = q.z; xf[i*4+3] = q.w;
            }
            const int col0 = (r*16 + s16)*5;
            #pragma unroll
            for (int t = 0; t < 5; t++) {
                float z0 = 0.f, z1 = 0.f;
                #pragma unroll
                for (int k = 0; k < 10; k++) {
                    const float w = W2p[k*5 + t];              // SGPR operand
                    z0 = fmaf(xf[k],      w, z0);
                    z1 = fmaf(xf[10 + k], w, z1);
                }
                const unsigned int pk =
                    (unsigned int)f2bf(z0) | ((unsigned int)f2bf(z1) << 16);
                // rows 2*r20, 2*r20+1 are adjacent in k -> single b32 store
                *(unsigned int*)(sZ + (col0 + t)*48 + 2*r20) = pk;
            }
        }
    }
    __syncthreads();

    // ---- stage 2: MFMA GEMM + X3 epilogue (unchanged from r3) ----
    const int quad = lane >> 4;
    const int m    = lane & 15;
    const int colBase = wave * 64;

    bf16x8 Bf[4][2];
    const bf16x8 z8 = {0,0,0,0,0,0,0,0};
    #pragma unroll
    for (int nt = 0; nt < 4; nt++) {
        const int col = colBase + nt*16 + m;
        Bf[nt][0] = *(const bf16x8*)(sZ + col*48 + quad*8);
        bf16x8 b1 = *(const bf16x8*)(sZ + col*48 + 32 + quad*8);  // quads 2,3 overflow
        Bf[nt][1] = (quad >= 2) ? z8 : b1;                         // k>=48 pad -> 0
    }

    float X3p[4][3];
    #pragma unroll
    for (int nt = 0; nt < 4; nt++)
        #pragma unroll
        for (int j = 0; j < 3; j++) X3p[nt][j] = 0.f;

    const f32x4v zacc = {0.f, 0.f, 0.f, 0.f};
    #pragma unroll
    for (int mt = 0; mt < 8; mt++) {
        const unsigned short* arow = sW1 + (mt*16 + m)*48;
        const bf16x8 A0 = *(const bf16x8*)(arow + quad*8);
        const bf16x8 A1 = *(const bf16x8*)(arow + 32 + quad*8);   // overflow -> row128=0
        f32x4v wp[4];
        #pragma unroll
        for (int r = 0; r < 4; r++)
            wp[r] = *(const f32x4v*)(sWp + (mt*16 + quad*4 + r)*4);
        #pragma unroll
        for (int nt = 0; nt < 4; nt++) {
            f32x4v acc = __builtin_amdgcn_mfma_f32_16x16x32_bf16(A0, Bf[nt][0], zacc, 0, 0, 0);
            acc = __builtin_amdgcn_mfma_f32_16x16x32_bf16(A1, Bf[nt][1], acc, 0, 0, 0);
            #pragma unroll
            for (int r = 0; r < 4; r++) {
                const float h = fmaxf(acc[r], 0.f);               // bias folded in GEMM
                X3p[nt][0] = fmaf(wp[r][0], h, X3p[nt][0]);
                X3p[nt][1] = fmaf(wp[r][1], h, X3p[nt][1]);
                X3p[nt][2] = fmaf(wp[r][2], h, X3p[nt][2]);
            }
        }
    }

    #pragma unroll
    for (int nt = 0; nt < 4; nt++) {
        #pragma unroll
        for (int j = 0; j < 3; j++) {
            float v = X3p[nt][j];
            v += __shfl_xor(v, 16, 64);
            v += __shfl_xor(v, 32, 64);
            X3p[nt][j] = v;
        }
    }
    if (quad == 0) {
        #pragma unroll
        for (int nt = 0; nt < 4; nt++) {
            const int col = colBase + nt*16 + m;
            sX3[col*3 + 0] = X3p[nt][0];
            sX3[col*3 + 1] = X3p[nt][1];
            sX3[col*3 + 2] = X3p[nt][2];
        }
    }
    __syncthreads();

    // ---- stage 3: attention + output softmax, one thread per sample ----
    if (tid < 64) {
        const int sGlob = blockIdx.x * 64 + tid;
        float X3v[3][5];
        #pragma unroll
        for (int t = 0; t < 5; t++)
            #pragma unroll
            for (int j = 0; j < 3; j++)
                X3v[j][t] = sX3[(tid*5 + t)*3 + j];

        const float lam  = sC[33];
        const float olam = 1.f - lam;
        float y[3];
        #pragma unroll
        for (int j = 0; j < 3; j++) {
            float S[5];
            #pragma unroll
            for (int t = 0; t < 5; t++) {
                float a = 0.f;
                #pragma unroll
                for (int k = 0; k < 5; k++)
                    a = fmaf(X3v[j][k], sC[k*5 + t], a);
                S[t] = a;
            }
            float mx = S[0];
            #pragma unroll
            for (int t = 1; t < 5; t++) mx = fmaxf(mx, S[t]);
            float ex[5], se = 0.f;
            #pragma unroll
            for (int t = 0; t < 5; t++) { ex[t] = __expf(S[t] - mx); se += ex[t]; }
            const float inv = 1.f / se;
            float yj = sC[30 + j];
            #pragma unroll
            for (int t = 0; t < 5; t++) {
                const float a  = ex[t] * inv;
                const float xc = X3v[j][t] * (lam + olam * a);
                yj = fmaf(xc, sC[25 + t], yj);
            }
            y[j] = yj;
        }
        const float mx = fmaxf(y[0], fmaxf(y[1], y[2]));
        const float e0 = __expf(y[0]-mx), e1 = __expf(y[1]-mx), e2 = __expf(y[2]-mx);
        const float inv = 1.f / (e0 + e1 + e2);
        if (sGlob < nsamp) {
            float* o = out + (size_t)sGlob*3;
            o[0] = e0*inv; o[1] = e1*inv; o[2] = e2*inv;
        }
    }
}

extern "C" void kernel_launch(void* const* d_in, const int* in_sizes, int n_in,
                              void* d_out, int out_size, void* d_ws, size_t ws_size,
                              hipStream_t stream) {
    const float* x   = (const float*)d_in[0];
    const float* W1  = (const float*)d_in[1];
    const float* W2  = (const float*)d_in[2];
    const float* B   = (const float*)d_in[3];
    const float* Tw1 = (const float*)d_in[4];
    const float* Tw  = (const float*)d_in[5];
    const float* Tw2 = (const float*)d_in[6];
    const float* TB  = (const float*)d_in[7];
    const float* l   = (const float*)d_in[8];
    float* out = (float*)d_out;
    float* ws  = (float*)d_ws;

    hipLaunchKernelGGL(prep_kernel, dim3(1), dim3(NTP), 0, stream,
                       W1, W2, B, Tw1, Tw, Tw2, TB, l, ws);

    const int nsamp = in_sizes[0] / 400;
    const int grid  = (nsamp + 63) / 64;
    hipLaunchKernelGGL(btabl_main, dim3(grid), dim3(NTM), 0, stream,
                       x, ws, out, nsamp);
}